// Round 1
// baseline (493.353 us; speedup 1.0000x reference)
//
#include <hip/hip_runtime.h>
#include <stdint.h>
#include <stddef.h>

typedef unsigned short u16;
typedef __attribute__((ext_vector_type(8))) short short8;   // 8 x bf16 MFMA A/B frag
typedef __attribute__((ext_vector_type(4))) float float4v;  // MFMA C/D frag

typedef const __attribute__((address_space(1))) void* gas_p;
typedef __attribute__((address_space(3))) void* las_p;

__device__ __forceinline__ float bf2f(u16 h) {
  union { unsigned u; float f; } v; v.u = ((unsigned)h) << 16; return v.f;
}
__device__ __forceinline__ u16 f2bf(float f) {
  union { float f; unsigned u; } v; v.f = f;
  return (u16)((v.u + 0x7FFFu + ((v.u >> 16) & 1u)) >> 16);
}

// ---------------------------------------------------------------------------
__global__ __launch_bounds__(256) void detect_kernel(const u16* __restrict__ src,
                                                     int* __restrict__ flag) {
  __shared__ int cnt[256];
  int c = 0;
  for (int j = 0; j < 256; j++) {
    const u16 w = src[threadIdx.x + j * 256];
    c += (((w >> 7) & 0xFF) == 0xFF) ? 1 : 0;
  }
  cnt[threadIdx.x] = c;
  __syncthreads();
  if (threadIdx.x == 0) {
    int t = 0;
    for (int i = 0; i < 256; i++) t += cnt[i];
    *flag = (t > 0) ? 1 : 0;
  }
}

__global__ __launch_bounds__(256) void cvt_bf16_kernel(const void* __restrict__ src,
                                                       const int* __restrict__ flag,
                                                       u16* __restrict__ dst, int n) {
  const int f = *flag;
  const int stride = gridDim.x * 256;
  for (int i = blockIdx.x * 256 + threadIdx.x; i < n; i += stride)
    dst[i] = f ? f2bf(((const float*)src)[i]) : ((const u16*)src)[i];
}

__global__ __launch_bounds__(256) void cvt_f32_kernel(const void* __restrict__ src,
                                                      const int* __restrict__ flag,
                                                      float* __restrict__ dst, int n) {
  const int f = *flag;
  const int stride = gridDim.x * 256;
  for (int i = blockIdx.x * 256 + threadIdx.x; i < n; i += stride)
    dst[i] = f ? ((const float*)src)[i] : bf2f(((const u16*)src)[i]);
}

__global__ __launch_bounds__(256) void cvt_transpose_kernel(
    const void* __restrict__ src, const int* __restrict__ flag,
    u16* __restrict__ dst, int R, int C) {
  __shared__ u16 tile[64][65];
  const int f = *flag;
  const int c0 = blockIdx.x * 64, r0 = blockIdx.y * 64;
  const int tc = threadIdx.x & 63;
  const int tr0 = (threadIdx.x >> 6) * 16;
#pragma unroll
  for (int i = 0; i < 16; i++) {
    const size_t idx = (size_t)(r0 + tr0 + i) * C + c0 + tc;
    tile[tr0 + i][tc] = f ? f2bf(((const float*)src)[idx]) : ((const u16*)src)[idx];
  }
  __syncthreads();
#pragma unroll
  for (int i = 0; i < 16; i++)
    dst[(size_t)(c0 + tr0 + i) * R + r0 + tc] = tile[tc][tr0 + i];
}

// ---------------------------------------------------------------------------
// C[M][N] = A[M][K] @ Bt[N][K]^T + bias[N]  (bf16 in, fp32 accum)
// m97 structure + XOR chunk swizzle on the GLOBAL fetch address:
// LDS[row][slot] = G[row][slot ^ (row&7)]  -> fragment reads conflict-free.
// ---------------------------------------------------------------------------
__global__ __launch_bounds__(256) void gemm_bt_kernel(
    const u16* __restrict__ A, const u16* __restrict__ Bt,
    const float* __restrict__ bias, void* __restrict__ C,
    int M, int N, int K, int out32) {
  __shared__ u16 As[128 * 64];
  __shared__ u16 Bs[128 * 64];
  const int tid = threadIdx.x;
  const int wave = tid >> 6, lane = tid & 63;
  const int wm = wave & 1, wn = wave >> 1;
  const int m0 = blockIdx.y * 128, n0 = blockIdx.x * 128;
  const int lr = lane >> 3, lc = lane & 7;
  const int quad = lane >> 4, l15 = lane & 15;

  float4v acc[4][4];
#pragma unroll
  for (int t = 0; t < 4; t++)
#pragma unroll
    for (int u = 0; u < 4; u++) acc[t][u] = (float4v){0.f, 0.f, 0.f, 0.f};

  for (int k0 = 0; k0 < K; k0 += 64) {
    __syncthreads();
#pragma unroll
    for (int i = 0; i < 4; i++) {
      const int brow = wave * 32 + i * 8;
      const int row = brow + lr;
      const int cG = lc ^ (row & 7);
      __builtin_amdgcn_global_load_lds(
          (gas_p)(A + (size_t)(m0 + row) * K + k0 + cG * 8),
          (las_p)(As + brow * 64), 16, 0, 0);
      __builtin_amdgcn_global_load_lds(
          (gas_p)(Bt + (size_t)(n0 + row) * K + k0 + cG * 8),
          (las_p)(Bs + brow * 64), 16, 0, 0);
    }
    __syncthreads();
#pragma unroll
    for (int ks = 0; ks < 2; ks++) {
      short8 af[4], bfr[4];
#pragma unroll
      for (int t = 0; t < 4; t++) {
        const int ar = wm * 64 + t * 16 + l15;
        af[t] = *(const short8*)(As + ar * 64 + ((ks * 4 + quad) ^ (ar & 7)) * 8);
        const int br = wn * 64 + t * 16 + l15;
        bfr[t] = *(const short8*)(Bs + br * 64 + ((ks * 4 + quad) ^ (br & 7)) * 8);
      }
#pragma unroll
      for (int t = 0; t < 4; t++)
#pragma unroll
        for (int u = 0; u < 4; u++)
          acc[t][u] = __builtin_amdgcn_mfma_f32_16x16x32_bf16(af[t], bfr[u], acc[t][u], 0, 0, 0);
    }
  }

  const int qr = quad << 2;
#pragma unroll
  for (int t = 0; t < 4; t++) {
    const int mrow = m0 + wm * 64 + t * 16 + qr;
#pragma unroll
    for (int u = 0; u < 4; u++) {
      const int col = n0 + wn * 64 + u * 16 + l15;
      const float bv = bias[col];
#pragma unroll
      for (int r = 0; r < 4; r++) {
        const float val = acc[t][u][r] + bv;
        if (out32) ((float*)C)[(size_t)(mrow + r) * N + col] = val;
        else       ((u16*)C)[(size_t)(mrow + r) * N + col] = f2bf(val);
      }
    }
  }
}

// ---------------------------------------------------------------------------
#define FA_S 2048
#define FA_D 1024
#define FA_LD 3072
#define NEG_BIG (-1e30f)

// ---------------------------------------------------------------------------
// One-shot V pre-transpose: qkv V-region [b,s,h,hd] -> vt[bh][hd][s].
// 64x64 tiles via LDS; XOR swizzle ((row>>3)&7)*8 keeps the column-gather
// reads <=2-way bank-conflicted while preserving 16B-aligned short8 rows.
// ---------------------------------------------------------------------------
__global__ __launch_bounds__(256) void vtrans_kernel(const u16* __restrict__ qkv,
                                                     u16* __restrict__ vt) {
  __shared__ __align__(16) u16 tile[64][72];
  const int tid = threadIdx.x;
  const int bh = blockIdx.y, b = bh >> 4, h = bh & 15;
  const int s0 = blockIdx.x * 64;
#pragma unroll
  for (int i = 0; i < 2; i++) {
    const int c = tid + i * 256;
    const int row = c >> 3, col = (c & 7) * 8;
    const int cs = col ^ (((row >> 3) & 7) * 8);
    *(short8*)(&tile[row][cs]) =
        *(const short8*)(qkv + (size_t)(b * FA_S + s0 + row) * FA_LD + 2 * FA_D + h * 64 + col);
  }
  __syncthreads();
#pragma unroll
  for (int i = 0; i < 2; i++) {
    const int c = tid + i * 256;
    const int hd = c >> 3, scol = (c & 7) * 8;
    const int xr = ((scol >> 3) & 7) * 8;
    __align__(16) u16 tmp[8];
#pragma unroll
    for (int j = 0; j < 8; j++) tmp[j] = tile[scol + j][hd ^ xr];
    *(short8*)(vt + (size_t)bh * (64 * FA_S) + (size_t)hd * FA_S + s0 + scol) =
        *(const short8*)tmp;
  }
}

// ---------------------------------------------------------------------------
// Flash attention (causal), barrier-free. 64-row Q-tiles; each block takes
// the complementary pair (qt, 31-qt) -> 33 K-iterations (perfect balance).
// K fragments are read DIRECTLY from global qkv (B-fragment layout == global
// layout; tiles are L1/L2-resident and reused by 16 q-blocks). V fragments
// read directly from the pre-transposed vt. No LDS staging, no
// __syncthreads -> waves run independently; s_setprio(1) wraps the MFMA
// clusters (T5: pays exactly in this independent-wave structure).
// P->PV stays an intra-wave LDS round-trip (DS program order, no barrier).
// Q pre-scaled by 0.125 (exact). Diagonal-only causal compare.
// ---------------------------------------------------------------------------
__global__ __launch_bounds__(256) void flash_kernel(
    const u16* __restrict__ qkv, const u16* __restrict__ vt,
    const float* __restrict__ am, u16* __restrict__ aout) {
  __shared__ u16 Ps[4][16 * 72];   // per-wave P [qrow][key]

  const int tid = threadIdx.x, wave = tid >> 6, lane = tid & 63;
  const int qp = blockIdx.x;           // 0..15 -> tiles {qp, 31-qp}
  const int bh = blockIdx.y, b = bh >> 4, h = bh & 15;
  const size_t rowbase = (size_t)b * FA_S;
  const int quad = lane >> 4, l15 = lane & 15;
  const float* amrow0 = am + b * FA_S;

  // lane-invariant fragment base pointers
  const u16* kptr = qkv + (rowbase * FA_LD) + FA_D + h * 64 + (size_t)l15 * FA_LD + quad * 8;
  const u16* vptr = vt + (size_t)bh * (64 * FA_S) + (size_t)l15 * FA_S + quad * 8;

  for (int ph = 0; ph < 2; ph++) {
    const int qt = ph ? (31 - qp) : qp;

    // Q fragments, pre-scaled by 1/8 (exact power of 2)
    short8 qf[2];
    {
      const int qrow = qt * 64 + wave * 16 + l15;
      const u16* qp_ = qkv + (rowbase + qrow) * FA_LD + h * 64 + quad * 8;
      __align__(16) u16 t0[8], t1[8];
      *(short8*)t0 = *(const short8*)qp_;
      *(short8*)t1 = *(const short8*)(qp_ + 32);
#pragma unroll
      for (int j = 0; j < 8; j++) {
        t0[j] = f2bf(bf2f(t0[j]) * 0.125f);
        t1[j] = f2bf(bf2f(t1[j]) * 0.125f);
      }
      qf[0] = *(const short8*)t0;
      qf[1] = *(const short8*)t1;
    }

    float m_i[4], l_i[4];
    float4v o[4];
#pragma unroll
    for (int r = 0; r < 4; r++) { m_i[r] = NEG_BIG; l_i[r] = 0.f; }
#pragma unroll
    for (int u = 0; u < 4; u++) o[u] = (float4v){0.f, 0.f, 0.f, 0.f};
    const int qrg = qt * 64 + wave * 16 + quad * 4;

    for (int kt = 0; kt <= qt; kt++) {
      // --- K fragments direct from global (L1/L2-resident tile) ---
      short8 kf[2][4];
#pragma unroll
      for (int ks = 0; ks < 2; ks++)
#pragma unroll
        for (int nt = 0; nt < 4; nt++)
          kf[ks][nt] = *(const short8*)(kptr + (size_t)(kt * 64 + nt * 16) * FA_LD + ks * 32);
      // --- V fragments direct from pre-transposed vt; issued early so
      //     softmax VALU (~500 cyc) hides the load latency ---
      short8 vf[2][4];
#pragma unroll
      for (int ks = 0; ks < 2; ks++)
#pragma unroll
        for (int u = 0; u < 4; u++)
          vf[ks][u] = *(const short8*)(vptr + (size_t)(u * 16) * FA_S + kt * 64 + ks * 32);

      // --- S = Q K^T ---
      float4v s[4];
#pragma unroll
      for (int nt = 0; nt < 4; nt++) s[nt] = (float4v){0.f, 0.f, 0.f, 0.f};
      __builtin_amdgcn_s_setprio(1);
#pragma unroll
      for (int ks = 0; ks < 2; ks++)
#pragma unroll
        for (int nt = 0; nt < 4; nt++)
          s[nt] = __builtin_amdgcn_mfma_f32_16x16x32_bf16(qf[ks], kf[ks][nt], s[nt], 0, 0, 0);
      __builtin_amdgcn_s_setprio(0);

      // --- mask + online softmax ---
      float mcur[4] = {NEG_BIG, NEG_BIG, NEG_BIG, NEG_BIG};
      const float* amrow = amrow0 + kt * 64;
      if (kt == qt) {  // diagonal tile: causal compare needed
#pragma unroll
        for (int nt = 0; nt < 4; nt++) {
          const int key_l = nt * 16 + l15;
          const float amv = amrow[key_l];
          const int key_g = kt * 64 + key_l;
#pragma unroll
          for (int r = 0; r < 4; r++) {
            float v = (key_g <= qrg + r) ? s[nt][r] : -10000.0f;
            v += amv;
            s[nt][r] = v;
            mcur[r] = fmaxf(mcur[r], v);
          }
        }
      } else {
#pragma unroll
        for (int nt = 0; nt < 4; nt++) {
          const float amv = amrow[nt * 16 + l15];
#pragma unroll
          for (int r = 0; r < 4; r++) {
            const float v = s[nt][r] + amv;
            s[nt][r] = v;
            mcur[r] = fmaxf(mcur[r], v);
          }
        }
      }
#pragma unroll
      for (int d = 1; d < 16; d <<= 1)
#pragma unroll
        for (int r = 0; r < 4; r++) mcur[r] = fmaxf(mcur[r], __shfl_xor(mcur[r], d, 64));
      float alpha[4];
#pragma unroll
      for (int r = 0; r < 4; r++) {
        const float mn = fmaxf(m_i[r], mcur[r]);
        alpha[r] = __expf(m_i[r] - mn);
        m_i[r] = mn;
      }
      float lsum[4] = {0.f, 0.f, 0.f, 0.f};
#pragma unroll
      for (int nt = 0; nt < 4; nt++)
#pragma unroll
        for (int r = 0; r < 4; r++) {
          const float e = __expf(s[nt][r] - m_i[r]);
          s[nt][r] = e;
          lsum[r] += e;
        }
#pragma unroll
      for (int d = 1; d < 16; d <<= 1)
#pragma unroll
        for (int r = 0; r < 4; r++) lsum[r] += __shfl_xor(lsum[r], d, 64);
#pragma unroll
      for (int r = 0; r < 4; r++) l_i[r] = l_i[r] * alpha[r] + lsum[r];
#pragma unroll
      for (int u = 0; u < 4; u++)
#pragma unroll
        for (int r = 0; r < 4; r++) o[u][r] *= alpha[r];

      // --- P -> own-wave LDS (intra-wave: DS program order, no barrier) ---
      u16* Pw = Ps[wave];
#pragma unroll
      for (int nt = 0; nt < 4; nt++) {
        const int col = nt * 16 + l15;
#pragma unroll
        for (int r = 0; r < 4; r++)
          Pw[(quad * 4 + r) * 72 + col] = f2bf(s[nt][r]);
      }

      // --- O += P V ---
      __builtin_amdgcn_s_setprio(1);
#pragma unroll
      for (int ks = 0; ks < 2; ks++) {
        const short8 pf = *(const short8*)(Pw + l15 * 72 + (ks * 4 + quad) * 8);
#pragma unroll
        for (int u = 0; u < 4; u++)
          o[u] = __builtin_amdgcn_mfma_f32_16x16x32_bf16(pf, vf[ks][u], o[u], 0, 0, 0);
      }
      __builtin_amdgcn_s_setprio(0);
    }

    // --- epilogue for this Q-tile (registers + global only) ---
#pragma unroll
    for (int u = 0; u < 4; u++) {
      const int col = h * 64 + u * 16 + l15;
#pragma unroll
      for (int r = 0; r < 4; r++) {
        const float val = o[u][r] / l_i[r];
        aout[(rowbase + qrg + r) * FA_D + col] = f2bf(val);
      }
    }
  }
}

// ---------------------------------------------------------------------------
extern "C" void kernel_launch(void* const* d_in, const int* in_sizes, int n_in,
                              void* d_out, int out_size, void* d_ws, size_t ws_size,
                              hipStream_t stream) {
  (void)out_size; (void)ws_size;
  auto find = [&](int count, int def_idx) -> const void* {
    for (int i = 0; i < n_in; i++)
      if (in_sizes[i] == count) return d_in[i];
    return d_in[def_idx];
  };
  const void* x  = find(8388608, 0);
  const void* am = find(8192, 1);
  const void* Wa = find(3145728, 2);
  const void* ba = find(3072, 3);
  const void* Wp = find(1048576, 4);
  const void* bp = find(1024, 5);

  char* ws = (char*)d_ws;
  u16*   x_c  = (u16*)(ws + 0);
  u16*   Wa_t = (u16*)(ws + 16777216);
  u16*   Wp_t = (u16*)(ws + 23068672);
  u16*   qkv  = (u16*)(ws + 25165824);
  u16*   abuf = (u16*)(ws + 75497472);
  float* ba_f = (float*)(ws + 92274688);
  float* bp_f = (float*)(ws + 92286976);
  float* am_f = (float*)(ws + 92291072);
  int*   flag = (int*)(ws + 92323840);
  // V^T [bh][hd][S] = 64*64*2048*2 B = 16,777,216 B: exactly fits the x_c
  // region, which is dead after the first GEMM (stream-ordered reuse).
  u16*   vt   = (u16*)(ws + 0);

  const int M = 8192, D = 1024;

  detect_kernel<<<1, 256, 0, stream>>>((const u16*)x, flag);
  cvt_bf16_kernel<<<2048, 256, 0, stream>>>(x, flag, x_c, M * D);
  cvt_f32_kernel<<<12, 256, 0, stream>>>(ba, flag, ba_f, 3072);
  cvt_f32_kernel<<<4, 256, 0, stream>>>(bp, flag, bp_f, 1024);
  cvt_f32_kernel<<<32, 256, 0, stream>>>(am, flag, am_f, 4 * FA_S);
  cvt_transpose_kernel<<<dim3(3072 / 64, 1024 / 64), 256, 0, stream>>>(Wa, flag, Wa_t, 1024, 3072);
  cvt_transpose_kernel<<<dim3(1024 / 64, 1024 / 64), 256, 0, stream>>>(Wp, flag, Wp_t, 1024, 1024);

  gemm_bt_kernel<<<dim3(3072 / 128, M / 128), 256, 0, stream>>>(
      x_c, Wa_t, ba_f, qkv, M, 3072, D, 0);
  vtrans_kernel<<<dim3(FA_S / 64, 64), 256, 0, stream>>>(qkv, vt);
  flash_kernel<<<dim3(16, 64), 256, 0, stream>>>(qkv, vt, am_f, abuf);
  gemm_bt_kernel<<<dim3(D / 128, M / 128), 256, 0, stream>>>(
      abuf, Wp_t, bp_f, d_out, M, D, D, 1);
}

// Round 2
// 387.645 us; speedup vs baseline: 1.2727x; 1.2727x over previous
//
#include <hip/hip_runtime.h>
#include <stdint.h>
#include <stddef.h>

typedef unsigned short u16;
typedef __attribute__((ext_vector_type(8))) short short8;   // 8 x bf16 MFMA A/B frag
typedef __attribute__((ext_vector_type(4))) float float4v;  // MFMA C/D frag

typedef const __attribute__((address_space(1))) void* gas_p;
typedef __attribute__((address_space(3))) void* las_p;

__device__ __forceinline__ float bf2f(u16 h) {
  union { unsigned u; float f; } v; v.u = ((unsigned)h) << 16; return v.f;
}
__device__ __forceinline__ u16 f2bf(float f) {
  union { float f; unsigned u; } v; v.f = f;
  return (u16)((v.u + 0x7FFFu + ((v.u >> 16) & 1u)) >> 16);
}

// ---------------------------------------------------------------------------
__global__ __launch_bounds__(256) void detect_kernel(const u16* __restrict__ src,
                                                     int* __restrict__ flag) {
  __shared__ int cnt[256];
  int c = 0;
  for (int j = 0; j < 256; j++) {
    const u16 w = src[threadIdx.x + j * 256];
    c += (((w >> 7) & 0xFF) == 0xFF) ? 1 : 0;
  }
  cnt[threadIdx.x] = c;
  __syncthreads();
  if (threadIdx.x == 0) {
    int t = 0;
    for (int i = 0; i < 256; i++) t += cnt[i];
    *flag = (t > 0) ? 1 : 0;
  }
}

__global__ __launch_bounds__(256) void cvt_bf16_kernel(const void* __restrict__ src,
                                                       const int* __restrict__ flag,
                                                       u16* __restrict__ dst, int n) {
  const int f = *flag;
  const int stride = gridDim.x * 256;
  for (int i = blockIdx.x * 256 + threadIdx.x; i < n; i += stride)
    dst[i] = f ? f2bf(((const float*)src)[i]) : ((const u16*)src)[i];
}

__global__ __launch_bounds__(256) void cvt_f32_kernel(const void* __restrict__ src,
                                                      const int* __restrict__ flag,
                                                      float* __restrict__ dst, int n) {
  const int f = *flag;
  const int stride = gridDim.x * 256;
  for (int i = blockIdx.x * 256 + threadIdx.x; i < n; i += stride)
    dst[i] = f ? ((const float*)src)[i] : bf2f(((const u16*)src)[i]);
}

__global__ __launch_bounds__(256) void cvt_transpose_kernel(
    const void* __restrict__ src, const int* __restrict__ flag,
    u16* __restrict__ dst, int R, int C) {
  __shared__ u16 tile[64][65];
  const int f = *flag;
  const int c0 = blockIdx.x * 64, r0 = blockIdx.y * 64;
  const int tc = threadIdx.x & 63;
  const int tr0 = (threadIdx.x >> 6) * 16;
#pragma unroll
  for (int i = 0; i < 16; i++) {
    const size_t idx = (size_t)(r0 + tr0 + i) * C + c0 + tc;
    tile[tr0 + i][tc] = f ? f2bf(((const float*)src)[idx]) : ((const u16*)src)[idx];
  }
  __syncthreads();
#pragma unroll
  for (int i = 0; i < 16; i++)
    dst[(size_t)(c0 + tr0 + i) * R + r0 + tc] = tile[tc][tr0 + i];
}

// ---------------------------------------------------------------------------
// C[M][N] = A[M][K] @ Bt[N][K]^T + bias[N]  (bf16 in, fp32 accum)
// m97 structure + XOR chunk swizzle on the GLOBAL fetch address:
// LDS[row][slot] = G[row][slot ^ (row&7)]  -> fragment reads conflict-free.
// ---------------------------------------------------------------------------
__global__ __launch_bounds__(256) void gemm_bt_kernel(
    const u16* __restrict__ A, const u16* __restrict__ Bt,
    const float* __restrict__ bias, void* __restrict__ C,
    int M, int N, int K, int out32) {
  __shared__ u16 As[128 * 64];
  __shared__ u16 Bs[128 * 64];
  const int tid = threadIdx.x;
  const int wave = tid >> 6, lane = tid & 63;
  const int wm = wave & 1, wn = wave >> 1;
  const int m0 = blockIdx.y * 128, n0 = blockIdx.x * 128;
  const int lr = lane >> 3, lc = lane & 7;
  const int quad = lane >> 4, l15 = lane & 15;

  float4v acc[4][4];
#pragma unroll
  for (int t = 0; t < 4; t++)
#pragma unroll
    for (int u = 0; u < 4; u++) acc[t][u] = (float4v){0.f, 0.f, 0.f, 0.f};

  for (int k0 = 0; k0 < K; k0 += 64) {
    __syncthreads();
#pragma unroll
    for (int i = 0; i < 4; i++) {
      const int brow = wave * 32 + i * 8;
      const int row = brow + lr;
      const int cG = lc ^ (row & 7);
      __builtin_amdgcn_global_load_lds(
          (gas_p)(A + (size_t)(m0 + row) * K + k0 + cG * 8),
          (las_p)(As + brow * 64), 16, 0, 0);
      __builtin_amdgcn_global_load_lds(
          (gas_p)(Bt + (size_t)(n0 + row) * K + k0 + cG * 8),
          (las_p)(Bs + brow * 64), 16, 0, 0);
    }
    __syncthreads();
#pragma unroll
    for (int ks = 0; ks < 2; ks++) {
      short8 af[4], bfr[4];
#pragma unroll
      for (int t = 0; t < 4; t++) {
        const int ar = wm * 64 + t * 16 + l15;
        af[t] = *(const short8*)(As + ar * 64 + ((ks * 4 + quad) ^ (ar & 7)) * 8);
        const int br = wn * 64 + t * 16 + l15;
        bfr[t] = *(const short8*)(Bs + br * 64 + ((ks * 4 + quad) ^ (br & 7)) * 8);
      }
#pragma unroll
      for (int t = 0; t < 4; t++)
#pragma unroll
        for (int u = 0; u < 4; u++)
          acc[t][u] = __builtin_amdgcn_mfma_f32_16x16x32_bf16(af[t], bfr[u], acc[t][u], 0, 0, 0);
    }
  }

  const int qr = quad << 2;
#pragma unroll
  for (int t = 0; t < 4; t++) {
    const int mrow = m0 + wm * 64 + t * 16 + qr;
#pragma unroll
    for (int u = 0; u < 4; u++) {
      const int col = n0 + wn * 64 + u * 16 + l15;
      const float bv = bias[col];
#pragma unroll
      for (int r = 0; r < 4; r++) {
        const float val = acc[t][u][r] + bv;
        if (out32) ((float*)C)[(size_t)(mrow + r) * N + col] = val;
        else       ((u16*)C)[(size_t)(mrow + r) * N + col] = f2bf(val);
      }
    }
  }
}

// ---------------------------------------------------------------------------
#define FA_S 2048
#define FA_D 1024
#define FA_LD 3072
#define NEG_BIG (-1e30f)

// ---------------------------------------------------------------------------
// One-shot V pre-transpose: qkv V-region [b,s,h,hd] -> vt[bh][hd][s].
// 64x64 tiles via LDS; XOR swizzle keeps reads <=2-way bank-conflicted while
// preserving 16B-aligned short8 rows. Verified (round-1 pass used vt).
// ---------------------------------------------------------------------------
__global__ __launch_bounds__(256) void vtrans_kernel(const u16* __restrict__ qkv,
                                                     u16* __restrict__ vt) {
  __shared__ __align__(16) u16 tile[64][72];
  const int tid = threadIdx.x;
  const int bh = blockIdx.y, b = bh >> 4, h = bh & 15;
  const int s0 = blockIdx.x * 64;
#pragma unroll
  for (int i = 0; i < 2; i++) {
    const int c = tid + i * 256;
    const int row = c >> 3, col = (c & 7) * 8;
    const int cs = col ^ (((row >> 3) & 7) * 8);
    *(short8*)(&tile[row][cs]) =
        *(const short8*)(qkv + (size_t)(b * FA_S + s0 + row) * FA_LD + 2 * FA_D + h * 64 + col);
  }
  __syncthreads();
#pragma unroll
  for (int i = 0; i < 2; i++) {
    const int c = tid + i * 256;
    const int hd = c >> 3, scol = (c & 7) * 8;
    const int xr = ((scol >> 3) & 7) * 8;
    __align__(16) u16 tmp[8];
#pragma unroll
    for (int j = 0; j < 8; j++) tmp[j] = tile[scol + j][hd ^ xr];
    *(short8*)(vt + (size_t)bh * (64 * FA_S) + (size_t)hd * FA_S + s0 + scol) =
        *(const short8*)tmp;
  }
}

// ---------------------------------------------------------------------------
// Flash attention (causal). 64-row Q-tiles; each block processes the
// complementary pair (qt, 31-qt) -> exactly 33 K-iterations per block.
// K AND V (pre-transposed) staged via swizzled global_load_lds (coalesced,
// 16B/lane). Minimal 2-phase prefetch (catalog T3-minimum): next tile's
// STAGE issues at the top of the iteration, compute covers the latency,
// ONE __syncthreads per iteration (its implicit vmcnt(0) drain lands after
// ~1500 cyc of MFMA+softmax). P->PV intra-wave via per-wave LDS (DS program
// order, no barrier). Q pre-scaled by 0.125 (exact). Diagonal-only causal.
// ---------------------------------------------------------------------------
__global__ __launch_bounds__(256) void flash_kernel(
    const u16* __restrict__ qkv, const u16* __restrict__ vt,
    const float* __restrict__ am, u16* __restrict__ aout) {
  __shared__ u16 Ks[2][64 * 64];   // [key][slot], slot = chunk^(key&7)
  __shared__ u16 Vs[2][64 * 64];   // [hd][slot],  slot = chunk^(hd&7)
  __shared__ u16 Ps[4][16 * 72];   // per-wave P [qrow][key] (stride 72: 2-way free)

  const int tid = threadIdx.x, wave = tid >> 6, lane = tid & 63;
  const int qp = blockIdx.x;           // 0..15 -> tiles {qp, 31-qp}
  const int bh = blockIdx.y, b = bh >> 4, h = bh & 15;
  const size_t rowbase = (size_t)b * FA_S;
  const int quad = lane >> 4, l15 = lane & 15;
  const int lr = lane >> 3, lc = lane & 7;
  const float* amrow0 = am + b * FA_S;
  const u16* kbase = qkv + rowbase * FA_LD + FA_D + h * 64;
  const u16* vbase = vt + (size_t)bh * (64 * FA_S);

  for (int ph = 0; ph < 2; ph++) {
    const int qt = ph ? (31 - qp) : qp;

    // Q fragments, pre-scaled by 1/8 (exact power of 2)
    short8 qf[2];
    {
      const int qrow = qt * 64 + wave * 16 + l15;
      const u16* qp_ = qkv + (rowbase + qrow) * FA_LD + h * 64 + quad * 8;
      __align__(16) u16 t0[8], t1[8];
      *(short8*)t0 = *(const short8*)qp_;
      *(short8*)t1 = *(const short8*)(qp_ + 32);
#pragma unroll
      for (int j = 0; j < 8; j++) {
        t0[j] = f2bf(bf2f(t0[j]) * 0.125f);
        t1[j] = f2bf(bf2f(t1[j]) * 0.125f);
      }
      qf[0] = *(const short8*)t0;
      qf[1] = *(const short8*)t1;
    }

    float m_i[4], l_i[4];
    float4v o[4];
#pragma unroll
    for (int r = 0; r < 4; r++) { m_i[r] = NEG_BIG; l_i[r] = 0.f; }
#pragma unroll
    for (int u = 0; u < 4; u++) o[u] = (float4v){0.f, 0.f, 0.f, 0.f};
    const int qrg = qt * 64 + wave * 16 + quad * 4;

    int cur = 0;
    // --- prologue: stage kt=0 into buffer 0 ---
#pragma unroll
    for (int i = 0; i < 2; i++) {
      const int brow = wave * 16 + i * 8;
      const int row = brow + lr;
      const int cG = lc ^ (row & 7);
      __builtin_amdgcn_global_load_lds(
          (gas_p)(kbase + (size_t)row * FA_LD + cG * 8),
          (las_p)(Ks[0] + brow * 64), 16, 0, 0);
      __builtin_amdgcn_global_load_lds(
          (gas_p)(vbase + (size_t)row * FA_S + cG * 8),
          (las_p)(Vs[0] + brow * 64), 16, 0, 0);
    }
    __syncthreads();   // drains vmcnt(0): buffer 0 ready

    for (int kt = 0; kt <= qt; kt++) {
      // --- prefetch next tile into buf[cur^1] (latency hides under compute) ---
      if (kt < qt) {
#pragma unroll
        for (int i = 0; i < 2; i++) {
          const int brow = wave * 16 + i * 8;
          const int row = brow + lr;
          const int cG = lc ^ (row & 7);
          __builtin_amdgcn_global_load_lds(
              (gas_p)(kbase + (size_t)((kt + 1) * 64 + row) * FA_LD + cG * 8),
              (las_p)(Ks[cur ^ 1] + brow * 64), 16, 0, 0);
          __builtin_amdgcn_global_load_lds(
              (gas_p)(vbase + (size_t)row * FA_S + (kt + 1) * 64 + cG * 8),
              (las_p)(Vs[cur ^ 1] + brow * 64), 16, 0, 0);
        }
      }
      const u16* Kc = Ks[cur];
      const u16* Vc = Vs[cur];

      // --- S = Q K^T ---
      float4v s[4];
#pragma unroll
      for (int nt = 0; nt < 4; nt++) s[nt] = (float4v){0.f, 0.f, 0.f, 0.f};
      __builtin_amdgcn_s_setprio(1);
#pragma unroll
      for (int ks = 0; ks < 2; ks++) {
#pragma unroll
        for (int nt = 0; nt < 4; nt++) {
          const int kr = nt * 16 + l15;
          const short8 kf = *(const short8*)(Kc + kr * 64 + (((ks * 4 + quad) ^ (kr & 7)) << 3));
          s[nt] = __builtin_amdgcn_mfma_f32_16x16x32_bf16(qf[ks], kf, s[nt], 0, 0, 0);
        }
      }
      __builtin_amdgcn_s_setprio(0);

      // --- mask + online softmax ---
      float mcur[4] = {NEG_BIG, NEG_BIG, NEG_BIG, NEG_BIG};
      const float* amrow = amrow0 + kt * 64;
      if (kt == qt) {  // diagonal tile: causal compare needed
#pragma unroll
        for (int nt = 0; nt < 4; nt++) {
          const int key_l = nt * 16 + l15;
          const float amv = amrow[key_l];
          const int key_g = kt * 64 + key_l;
#pragma unroll
          for (int r = 0; r < 4; r++) {
            float v = (key_g <= qrg + r) ? s[nt][r] : -10000.0f;
            v += amv;
            s[nt][r] = v;
            mcur[r] = fmaxf(mcur[r], v);
          }
        }
      } else {
#pragma unroll
        for (int nt = 0; nt < 4; nt++) {
          const float amv = amrow[nt * 16 + l15];
#pragma unroll
          for (int r = 0; r < 4; r++) {
            const float v = s[nt][r] + amv;
            s[nt][r] = v;
            mcur[r] = fmaxf(mcur[r], v);
          }
        }
      }
#pragma unroll
      for (int d = 1; d < 16; d <<= 1)
#pragma unroll
        for (int r = 0; r < 4; r++) mcur[r] = fmaxf(mcur[r], __shfl_xor(mcur[r], d, 64));
      float alpha[4];
#pragma unroll
      for (int r = 0; r < 4; r++) {
        const float mn = fmaxf(m_i[r], mcur[r]);
        alpha[r] = __expf(m_i[r] - mn);
        m_i[r] = mn;
      }
      float lsum[4] = {0.f, 0.f, 0.f, 0.f};
#pragma unroll
      for (int nt = 0; nt < 4; nt++)
#pragma unroll
        for (int r = 0; r < 4; r++) {
          const float e = __expf(s[nt][r] - m_i[r]);
          s[nt][r] = e;
          lsum[r] += e;
        }
#pragma unroll
      for (int d = 1; d < 16; d <<= 1)
#pragma unroll
        for (int r = 0; r < 4; r++) lsum[r] += __shfl_xor(lsum[r], d, 64);
#pragma unroll
      for (int r = 0; r < 4; r++) l_i[r] = l_i[r] * alpha[r] + lsum[r];
#pragma unroll
      for (int u = 0; u < 4; u++)
#pragma unroll
        for (int r = 0; r < 4; r++) o[u][r] *= alpha[r];

      // --- P -> own-wave LDS (intra-wave: DS program order, no barrier) ---
      u16* Pw = Ps[wave];
#pragma unroll
      for (int nt = 0; nt < 4; nt++) {
        const int col = nt * 16 + l15;
#pragma unroll
        for (int r = 0; r < 4; r++)
          Pw[(quad * 4 + r) * 72 + col] = f2bf(s[nt][r]);
      }

      // --- O += P V ---
      __builtin_amdgcn_s_setprio(1);
#pragma unroll
      for (int ks = 0; ks < 2; ks++) {
        const short8 pf = *(const short8*)(Pw + l15 * 72 + (ks * 4 + quad) * 8);
#pragma unroll
        for (int u = 0; u < 4; u++) {
          const int n = u * 16 + l15;
          const short8 vf = *(const short8*)(Vc + n * 64 + (((ks * 4 + quad) ^ (n & 7)) << 3));
          o[u] = __builtin_amdgcn_mfma_f32_16x16x32_bf16(pf, vf, o[u], 0, 0, 0);
        }
      }
      __builtin_amdgcn_s_setprio(0);

      // one barrier per iteration: all waves done reading buf[cur], and the
      // implicit vmcnt(0) drain completes the prefetch into buf[cur^1].
      __syncthreads();
      cur ^= 1;
    }

    // --- epilogue for this Q-tile (registers + global only) ---
#pragma unroll
    for (int u = 0; u < 4; u++) {
      const int col = h * 64 + u * 16 + l15;
#pragma unroll
      for (int r = 0; r < 4; r++) {
        const float val = o[u][r] / l_i[r];
        aout[(rowbase + qrg + r) * FA_D + col] = f2bf(val);
      }
    }
  }
}

// ---------------------------------------------------------------------------
extern "C" void kernel_launch(void* const* d_in, const int* in_sizes, int n_in,
                              void* d_out, int out_size, void* d_ws, size_t ws_size,
                              hipStream_t stream) {
  (void)out_size; (void)ws_size;
  auto find = [&](int count, int def_idx) -> const void* {
    for (int i = 0; i < n_in; i++)
      if (in_sizes[i] == count) return d_in[i];
    return d_in[def_idx];
  };
  const void* x  = find(8388608, 0);
  const void* am = find(8192, 1);
  const void* Wa = find(3145728, 2);
  const void* ba = find(3072, 3);
  const void* Wp = find(1048576, 4);
  const void* bp = find(1024, 5);

  char* ws = (char*)d_ws;
  u16*   x_c  = (u16*)(ws + 0);
  u16*   Wa_t = (u16*)(ws + 16777216);
  u16*   Wp_t = (u16*)(ws + 23068672);
  u16*   qkv  = (u16*)(ws + 25165824);
  u16*   abuf = (u16*)(ws + 75497472);
  float* ba_f = (float*)(ws + 92274688);
  float* bp_f = (float*)(ws + 92286976);
  float* am_f = (float*)(ws + 92291072);
  int*   flag = (int*)(ws + 92323840);
  // V^T [bh][hd][S] = 64*64*2048*2 B = 16,777,216 B: exactly fits the x_c
  // region, which is dead after the first GEMM (stream-ordered reuse).
  u16*   vt   = (u16*)(ws + 0);

  const int M = 8192, D = 1024;

  detect_kernel<<<1, 256, 0, stream>>>((const u16*)x, flag);
  cvt_bf16_kernel<<<2048, 256, 0, stream>>>(x, flag, x_c, M * D);
  cvt_f32_kernel<<<12, 256, 0, stream>>>(ba, flag, ba_f, 3072);
  cvt_f32_kernel<<<4, 256, 0, stream>>>(bp, flag, bp_f, 1024);
  cvt_f32_kernel<<<32, 256, 0, stream>>>(am, flag, am_f, 4 * FA_S);
  cvt_transpose_kernel<<<dim3(3072 / 64, 1024 / 64), 256, 0, stream>>>(Wa, flag, Wa_t, 1024, 3072);
  cvt_transpose_kernel<<<dim3(1024 / 64, 1024 / 64), 256, 0, stream>>>(Wp, flag, Wp_t, 1024, 1024);

  gemm_bt_kernel<<<dim3(3072 / 128, M / 128), 256, 0, stream>>>(
      x_c, Wa_t, ba_f, qkv, M, 3072, D, 0);
  vtrans_kernel<<<dim3(FA_S / 64, 64), 256, 0, stream>>>(qkv, vt);
  flash_kernel<<<dim3(16, 64), 256, 0, stream>>>(qkv, vt, am_f, abuf);
  gemm_bt_kernel<<<dim3(D / 128, M / 128), 256, 0, stream>>>(
      abuf, Wp_t, bp_f, d_out, M, D, D, 1);
}

// Round 3
// 355.118 us; speedup vs baseline: 1.3893x; 1.0916x over previous
//
#include <hip/hip_runtime.h>
#include <stdint.h>
#include <stddef.h>

typedef unsigned short u16;
typedef __attribute__((ext_vector_type(8))) short short8;   // 8 x bf16 MFMA A/B frag
typedef __attribute__((ext_vector_type(4))) float float4v;  // MFMA C/D frag
typedef __attribute__((ext_vector_type(2))) unsigned uint2v;

typedef const __attribute__((address_space(1))) void* gas_p;
typedef __attribute__((address_space(3))) void* las_p;

__device__ __forceinline__ float bf2f(u16 h) {
  union { unsigned u; float f; } v; v.u = ((unsigned)h) << 16; return v.f;
}
__device__ __forceinline__ u16 f2bf(float f) {
  union { float f; unsigned u; } v; v.f = f;
  return (u16)((v.u + 0x7FFFu + ((v.u >> 16) & 1u)) >> 16);
}
// packed f32->bf16 (RNE), gfx950. No builtin exists (m240); inline asm.
__device__ __forceinline__ unsigned cvt_pk_bf16(float lo, float hi) {
  unsigned r;
  asm("v_cvt_pk_bf16_f32 %0, %1, %2" : "=v"(r) : "v"(lo), "v"(hi));
  return r;
}

// ---------------------------------------------------------------------------
__global__ __launch_bounds__(256) void detect_kernel(const u16* __restrict__ src,
                                                     int* __restrict__ flag) {
  __shared__ int cnt[256];
  int c = 0;
  for (int j = 0; j < 256; j++) {
    const u16 w = src[threadIdx.x + j * 256];
    c += (((w >> 7) & 0xFF) == 0xFF) ? 1 : 0;
  }
  cnt[threadIdx.x] = c;
  __syncthreads();
  if (threadIdx.x == 0) {
    int t = 0;
    for (int i = 0; i < 256; i++) t += cnt[i];
    *flag = (t > 0) ? 1 : 0;
  }
}

__global__ __launch_bounds__(256) void cvt_bf16_kernel(const void* __restrict__ src,
                                                       const int* __restrict__ flag,
                                                       u16* __restrict__ dst, int n) {
  const int f = *flag;
  const int stride = gridDim.x * 256;
  for (int i = blockIdx.x * 256 + threadIdx.x; i < n; i += stride)
    dst[i] = f ? f2bf(((const float*)src)[i]) : ((const u16*)src)[i];
}

__global__ __launch_bounds__(256) void cvt_f32_kernel(const void* __restrict__ src,
                                                      const int* __restrict__ flag,
                                                      float* __restrict__ dst, int n) {
  const int f = *flag;
  const int stride = gridDim.x * 256;
  for (int i = blockIdx.x * 256 + threadIdx.x; i < n; i += stride)
    dst[i] = f ? ((const float*)src)[i] : bf2f(((const u16*)src)[i]);
}

__global__ __launch_bounds__(256) void cvt_transpose_kernel(
    const void* __restrict__ src, const int* __restrict__ flag,
    u16* __restrict__ dst, int R, int C) {
  __shared__ u16 tile[64][65];
  const int f = *flag;
  const int c0 = blockIdx.x * 64, r0 = blockIdx.y * 64;
  const int tc = threadIdx.x & 63;
  const int tr0 = (threadIdx.x >> 6) * 16;
#pragma unroll
  for (int i = 0; i < 16; i++) {
    const size_t idx = (size_t)(r0 + tr0 + i) * C + c0 + tc;
    tile[tr0 + i][tc] = f ? f2bf(((const float*)src)[idx]) : ((const u16*)src)[idx];
  }
  __syncthreads();
#pragma unroll
  for (int i = 0; i < 16; i++)
    dst[(size_t)(c0 + tr0 + i) * R + r0 + tc] = tile[tc][tr0 + i];
}

// ---------------------------------------------------------------------------
// C[M][N] = A[M][K] @ Bt[N][K]^T + bias[N]  (bf16 in, fp32 accum)
// ---------------------------------------------------------------------------
__global__ __launch_bounds__(256) void gemm_bt_kernel(
    const u16* __restrict__ A, const u16* __restrict__ Bt,
    const float* __restrict__ bias, void* __restrict__ C,
    int M, int N, int K, int out32) {
  __shared__ u16 As[128 * 64];
  __shared__ u16 Bs[128 * 64];
  const int tid = threadIdx.x;
  const int wave = tid >> 6, lane = tid & 63;
  const int wm = wave & 1, wn = wave >> 1;
  const int m0 = blockIdx.y * 128, n0 = blockIdx.x * 128;
  const int lr = lane >> 3, lc = lane & 7;
  const int quad = lane >> 4, l15 = lane & 15;

  float4v acc[4][4];
#pragma unroll
  for (int t = 0; t < 4; t++)
#pragma unroll
    for (int u = 0; u < 4; u++) acc[t][u] = (float4v){0.f, 0.f, 0.f, 0.f};

  for (int k0 = 0; k0 < K; k0 += 64) {
    __syncthreads();
#pragma unroll
    for (int i = 0; i < 4; i++) {
      const int brow = wave * 32 + i * 8;
      const int row = brow + lr;
      const int cG = lc ^ (row & 7);
      __builtin_amdgcn_global_load_lds(
          (gas_p)(A + (size_t)(m0 + row) * K + k0 + cG * 8),
          (las_p)(As + brow * 64), 16, 0, 0);
      __builtin_amdgcn_global_load_lds(
          (gas_p)(Bt + (size_t)(n0 + row) * K + k0 + cG * 8),
          (las_p)(Bs + brow * 64), 16, 0, 0);
    }
    __syncthreads();
#pragma unroll
    for (int ks = 0; ks < 2; ks++) {
      short8 af[4], bfr[4];
#pragma unroll
      for (int t = 0; t < 4; t++) {
        const int ar = wm * 64 + t * 16 + l15;
        af[t] = *(const short8*)(As + ar * 64 + ((ks * 4 + quad) ^ (ar & 7)) * 8);
        const int br = wn * 64 + t * 16 + l15;
        bfr[t] = *(const short8*)(Bs + br * 64 + ((ks * 4 + quad) ^ (br & 7)) * 8);
      }
#pragma unroll
      for (int t = 0; t < 4; t++)
#pragma unroll
        for (int u = 0; u < 4; u++)
          acc[t][u] = __builtin_amdgcn_mfma_f32_16x16x32_bf16(af[t], bfr[u], acc[t][u], 0, 0, 0);
    }
  }

  const int qr = quad << 2;
#pragma unroll
  for (int t = 0; t < 4; t++) {
    const int mrow = m0 + wm * 64 + t * 16 + qr;
#pragma unroll
    for (int u = 0; u < 4; u++) {
      const int col = n0 + wn * 64 + u * 16 + l15;
      const float bv = bias[col];
#pragma unroll
      for (int r = 0; r < 4; r++) {
        const float val = acc[t][u][r] + bv;
        if (out32) ((float*)C)[(size_t)(mrow + r) * N + col] = val;
        else       ((u16*)C)[(size_t)(mrow + r) * N + col] = f2bf(val);
      }
    }
  }
}

// ---------------------------------------------------------------------------
#define FA_S 2048
#define FA_D 1024
#define FA_LD 3072
#define NEG_BIG (-1e30f)

// ---------------------------------------------------------------------------
// One-shot V pre-transpose: qkv V-region [b,s,h,hd] -> vt[bh][hd][s].
// ---------------------------------------------------------------------------
__global__ __launch_bounds__(256) void vtrans_kernel(const u16* __restrict__ qkv,
                                                     u16* __restrict__ vt) {
  __shared__ __align__(16) u16 tile[64][72];
  const int tid = threadIdx.x;
  const int bh = blockIdx.y, b = bh >> 4, h = bh & 15;
  const int s0 = blockIdx.x * 64;
#pragma unroll
  for (int i = 0; i < 2; i++) {
    const int c = tid + i * 256;
    const int row = c >> 3, col = (c & 7) * 8;
    const int cs = col ^ (((row >> 3) & 7) * 8);
    *(short8*)(&tile[row][cs]) =
        *(const short8*)(qkv + (size_t)(b * FA_S + s0 + row) * FA_LD + 2 * FA_D + h * 64 + col);
  }
  __syncthreads();
#pragma unroll
  for (int i = 0; i < 2; i++) {
    const int c = tid + i * 256;
    const int hd = c >> 3, scol = (c & 7) * 8;
    const int xr = ((scol >> 3) & 7) * 8;
    __align__(16) u16 tmp[8];
#pragma unroll
    for (int j = 0; j < 8; j++) tmp[j] = tile[scol + j][hd ^ xr];
    *(short8*)(vt + (size_t)bh * (64 * FA_S) + (size_t)hd * FA_S + s0 + scol) =
        *(const short8*)tmp;
  }
}

// ---------------------------------------------------------------------------
// Flash attention (causal), SWAPPED-QK^T formulation (T12 adaptation).
// s[nt] = mfma(kf, qf) -> C[row=key_local=quad*4+r (+nt*16)][col=q=l15]:
// each lane holds 16 S-values of ONE q-row (q=l15) -> softmax reductions are
// in-lane (15 ops) + 2 cross-quad shfl_xor; m/l/alpha are per-lane scalars.
// P-write packs 4 consecutive keys per nt via 2x v_cvt_pk_bf16_f32 -> one
// ds_write_b64; the PV b128 read address pattern is unchanged. T13 defer-max
// skips the O-rescale when __all(mcur <= m+8). 2-phase K/V prefetch via
// swizzled global_load_lds, one barrier/iter (as round 2).
// ---------------------------------------------------------------------------
__global__ __launch_bounds__(256) void flash_kernel(
    const u16* __restrict__ qkv, const u16* __restrict__ vt,
    const float* __restrict__ am, u16* __restrict__ aout) {
  __shared__ u16 Ks[2][64 * 64];   // [key][slot], slot = chunk^(key&7)
  __shared__ u16 Vs[2][64 * 64];   // [hd][slot],  slot = chunk^(hd&7)
  __shared__ u16 Ps[4][16 * 72];   // per-wave P [q=l15][key] (stride 72)

  const int tid = threadIdx.x, wave = tid >> 6, lane = tid & 63;
  const int qp = blockIdx.x;           // 0..15 -> tiles {qp, 31-qp}
  const int bh = blockIdx.y, b = bh >> 4, h = bh & 15;
  const size_t rowbase = (size_t)b * FA_S;
  const int quad = lane >> 4, l15 = lane & 15;
  const int lr = lane >> 3, lc = lane & 7;
  const int wq = wave * 16 + l15;      // q-local within the 64-row tile
  const float* amrow0 = am + b * FA_S;
  const u16* kbase = qkv + rowbase * FA_LD + FA_D + h * 64;
  const u16* vbase = vt + (size_t)bh * (64 * FA_S);

  for (int ph = 0; ph < 2; ph++) {
    const int qt = ph ? (31 - qp) : qp;

    // Q fragments, pre-scaled by 1/8 (exact power of 2)
    short8 qf[2];
    {
      const int qrow = qt * 64 + wq;
      const u16* qp_ = qkv + (rowbase + qrow) * FA_LD + h * 64 + quad * 8;
      __align__(16) u16 t0[8], t1[8];
      *(short8*)t0 = *(const short8*)qp_;
      *(short8*)t1 = *(const short8*)(qp_ + 32);
#pragma unroll
      for (int j = 0; j < 8; j++) {
        t0[j] = f2bf(bf2f(t0[j]) * 0.125f);
        t1[j] = f2bf(bf2f(t1[j]) * 0.125f);
      }
      qf[0] = *(const short8*)t0;
      qf[1] = *(const short8*)t1;
    }

    float m_i = NEG_BIG, l_i = 0.f;   // per-lane scalars: stats of q-row l15
    float4v o[4];
#pragma unroll
    for (int u = 0; u < 4; u++) o[u] = (float4v){0.f, 0.f, 0.f, 0.f};
    const int qrg = qt * 64 + wave * 16 + quad * 4;  // o-row base (epilogue)

    int cur = 0;
    // --- prologue: stage kt=0 into buffer 0 ---
#pragma unroll
    for (int i = 0; i < 2; i++) {
      const int brow = wave * 16 + i * 8;
      const int row = brow + lr;
      const int cG = lc ^ (row & 7);
      __builtin_amdgcn_global_load_lds(
          (gas_p)(kbase + (size_t)row * FA_LD + cG * 8),
          (las_p)(Ks[0] + brow * 64), 16, 0, 0);
      __builtin_amdgcn_global_load_lds(
          (gas_p)(vbase + (size_t)row * FA_S + cG * 8),
          (las_p)(Vs[0] + brow * 64), 16, 0, 0);
    }
    __syncthreads();   // drains vmcnt(0): buffer 0 ready

    for (int kt = 0; kt <= qt; kt++) {
      // --- prefetch next tile into buf[cur^1] ---
      if (kt < qt) {
#pragma unroll
        for (int i = 0; i < 2; i++) {
          const int brow = wave * 16 + i * 8;
          const int row = brow + lr;
          const int cG = lc ^ (row & 7);
          __builtin_amdgcn_global_load_lds(
              (gas_p)(kbase + (size_t)((kt + 1) * 64 + row) * FA_LD + cG * 8),
              (las_p)(Ks[cur ^ 1] + brow * 64), 16, 0, 0);
          __builtin_amdgcn_global_load_lds(
              (gas_p)(vbase + (size_t)row * FA_S + (kt + 1) * 64 + cG * 8),
              (las_p)(Vs[cur ^ 1] + brow * 64), 16, 0, 0);
        }
      }
      const u16* Kc = Ks[cur];
      const u16* Vc = Vs[cur];

      // --- S^T = K Q^T (swapped operands; same fragments as before) ---
      float4v s[4];
#pragma unroll
      for (int nt = 0; nt < 4; nt++) s[nt] = (float4v){0.f, 0.f, 0.f, 0.f};
      __builtin_amdgcn_s_setprio(1);
#pragma unroll
      for (int ks = 0; ks < 2; ks++) {
#pragma unroll
        for (int nt = 0; nt < 4; nt++) {
          const int kr = nt * 16 + l15;
          const short8 kf = *(const short8*)(Kc + kr * 64 + (((ks * 4 + quad) ^ (kr & 7)) << 3));
          s[nt] = __builtin_amdgcn_mfma_f32_16x16x32_bf16(kf, qf[ks], s[nt], 0, 0, 0);
        }
      }
      __builtin_amdgcn_s_setprio(0);
      // lane now holds S[q=l15][key = nt*16 + quad*4 + r]

      // --- mask + am + row-max (in-lane over 16, then cross-quad) ---
      float mcur = NEG_BIG;
      const float* amrow = amrow0 + kt * 64;
      if (kt == qt) {  // diagonal tile: causal compare needed
#pragma unroll
        for (int nt = 0; nt < 4; nt++) {
          const float4v amv = *(const float4v*)(amrow + nt * 16 + (quad << 2));
#pragma unroll
          for (int r = 0; r < 4; r++) {
            const int kl = nt * 16 + (quad << 2) + r;
            float v = (kl <= wq) ? s[nt][r] : -10000.0f;
            v += amv[r];
            s[nt][r] = v;
            mcur = fmaxf(mcur, v);
          }
        }
      } else {
#pragma unroll
        for (int nt = 0; nt < 4; nt++) {
          const float4v amv = *(const float4v*)(amrow + nt * 16 + (quad << 2));
#pragma unroll
          for (int r = 0; r < 4; r++) {
            const float v = s[nt][r] + amv[r];
            s[nt][r] = v;
            mcur = fmaxf(mcur, v);
          }
        }
      }
      mcur = fmaxf(mcur, __shfl_xor(mcur, 16, 64));
      mcur = fmaxf(mcur, __shfl_xor(mcur, 32, 64));

      // --- T13 defer-max: only rescale when the max moved by >8 ---
      if (!__all(mcur <= m_i + 8.f)) {
        const float mn = fmaxf(m_i, mcur);
        const float alpha = __expf(m_i - mn);
        m_i = mn;
        l_i *= alpha;
        float ar[4];
#pragma unroll
        for (int r = 0; r < 4; r++) ar[r] = __shfl(alpha, (quad << 2) + r, 64);
#pragma unroll
        for (int u = 0; u < 4; u++)
#pragma unroll
          for (int r = 0; r < 4; r++) o[u][r] *= ar[r];
      }

      // --- P = exp(S - m), row-sum in-lane + cross-quad ---
      float lsum = 0.f;
#pragma unroll
      for (int nt = 0; nt < 4; nt++)
#pragma unroll
        for (int r = 0; r < 4; r++) {
          const float e = __expf(s[nt][r] - m_i);
          s[nt][r] = e;
          lsum += e;
        }
      lsum += __shfl_xor(lsum, 16, 64);
      lsum += __shfl_xor(lsum, 32, 64);
      l_i += lsum;

      // --- P -> own-wave LDS: 2x cvt_pk + 1x ds_write_b64 per nt ---
      u16* Pw = Ps[wave];
#pragma unroll
      for (int nt = 0; nt < 4; nt++) {
        const unsigned w0 = cvt_pk_bf16(s[nt][0], s[nt][1]);
        const unsigned w1 = cvt_pk_bf16(s[nt][2], s[nt][3]);
        uint2v ww; ww.x = w0; ww.y = w1;
        *(uint2v*)(Pw + l15 * 72 + nt * 16 + (quad << 2)) = ww;
      }

      // --- O += P V (pf read layout unchanged: b128 at [l15][ks*32+quad*8]) ---
      __builtin_amdgcn_s_setprio(1);
#pragma unroll
      for (int ks = 0; ks < 2; ks++) {
        const short8 pf = *(const short8*)(Pw + l15 * 72 + ks * 32 + quad * 8);
#pragma unroll
        for (int u = 0; u < 4; u++) {
          const int n = u * 16 + l15;
          const short8 vf = *(const short8*)(Vc + n * 64 + (((ks * 4 + quad) ^ (n & 7)) << 3));
          o[u] = __builtin_amdgcn_mfma_f32_16x16x32_bf16(pf, vf, o[u], 0, 0, 0);
        }
      }
      __builtin_amdgcn_s_setprio(0);

      __syncthreads();
      cur ^= 1;
    }

    // --- epilogue: per-o-row l via 4 shfls, then store ---
    float lr_[4];
#pragma unroll
    for (int r = 0; r < 4; r++) lr_[r] = __shfl(l_i, (quad << 2) + r, 64);
#pragma unroll
    for (int u = 0; u < 4; u++) {
      const int col = h * 64 + u * 16 + l15;
#pragma unroll
      for (int r = 0; r < 4; r++) {
        const float val = o[u][r] / lr_[r];
        aout[(rowbase + qrg + r) * FA_D + col] = f2bf(val);
      }
    }
  }
}

// ---------------------------------------------------------------------------
extern "C" void kernel_launch(void* const* d_in, const int* in_sizes, int n_in,
                              void* d_out, int out_size, void* d_ws, size_t ws_size,
                              hipStream_t stream) {
  (void)out_size; (void)ws_size;
  auto find = [&](int count, int def_idx) -> const void* {
    for (int i = 0; i < n_in; i++)
      if (in_sizes[i] == count) return d_in[i];
    return d_in[def_idx];
  };
  const void* x  = find(8388608, 0);
  const void* am = find(8192, 1);
  const void* Wa = find(3145728, 2);
  const void* ba = find(3072, 3);
  const void* Wp = find(1048576, 4);
  const void* bp = find(1024, 5);

  char* ws = (char*)d_ws;
  u16*   x_c  = (u16*)(ws + 0);
  u16*   Wa_t = (u16*)(ws + 16777216);
  u16*   Wp_t = (u16*)(ws + 23068672);
  u16*   qkv  = (u16*)(ws + 25165824);
  u16*   abuf = (u16*)(ws + 75497472);
  float* ba_f = (float*)(ws + 92274688);
  float* bp_f = (float*)(ws + 92286976);
  float* am_f = (float*)(ws + 92291072);
  int*   flag = (int*)(ws + 92323840);
  // V^T reuses the x_c region (dead after the first GEMM, stream-ordered).
  u16*   vt   = (u16*)(ws + 0);

  const int M = 8192, D = 1024;

  detect_kernel<<<1, 256, 0, stream>>>((const u16*)x, flag);
  cvt_bf16_kernel<<<2048, 256, 0, stream>>>(x, flag, x_c, M * D);
  cvt_f32_kernel<<<12, 256, 0, stream>>>(ba, flag, ba_f, 3072);
  cvt_f32_kernel<<<4, 256, 0, stream>>>(bp, flag, bp_f, 1024);
  cvt_f32_kernel<<<32, 256, 0, stream>>>(am, flag, am_f, 4 * FA_S);
  cvt_transpose_kernel<<<dim3(3072 / 64, 1024 / 64), 256, 0, stream>>>(Wa, flag, Wa_t, 1024, 3072);
  cvt_transpose_kernel<<<dim3(1024 / 64, 1024 / 64), 256, 0, stream>>>(Wp, flag, Wp_t, 1024, 1024);

  gemm_bt_kernel<<<dim3(3072 / 128, M / 128), 256, 0, stream>>>(
      x_c, Wa_t, ba_f, qkv, M, 3072, D, 0);
  vtrans_kernel<<<dim3(FA_S / 64, 64), 256, 0, stream>>>(qkv, vt);
  flash_kernel<<<dim3(16, 64), 256, 0, stream>>>(qkv, vt, am_f, abuf);
  gemm_bt_kernel<<<dim3(D / 128, M / 128), 256, 0, stream>>>(
      abuf, Wp_t, bp_f, d_out, M, D, D, 1);
}